// Round 22
// baseline (9815.688 us; speedup 1.0000x reference)
//
#include <hip/hip_runtime.h>
#include <math.h>

#define BB 2048
#define TT 512
#define NFEAT 25
#define UNITS 300
#define RPB 16
#define NBLK (BB/RPB)    // 128
#define NT 512
#define NW 8             // waves per block
#define NKS 11           // heads k-steps; fp8 h GEMM uses ks1-10
#define TPW 10           // tiles per wave (80 tiles / 8 waves)
#define HROW 360         // Hbf row stride (shorts); h at 32..331, 1.0 at 332
#define F8ROW 392        // Af8 row stride (bytes); h at 32..331
#define G2ROW 40         // G2b8 row stride (bytes); gates at 0..23
#define GROW 72

// d_ws layout (short offsets)
#define OFF_M1 0
#define SZ_M1  (4*2*512)             // 4096
#define OFF_M2 (OFF_M1 + SZ_M1)      // 4096
#define SZ_M2  (2*2*512)             // 2048
#define OFF_H  (OFF_M2 + SZ_M2)      // 6144
#define SZ_H   (2*NKS*512)           // 11264
#define OFF_BZ (OFF_H + SZ_H)        // 17408 : 1280 floats
#define OFF_WK (OFF_BZ + 2560)       // 19968 : 1280 floats
#define OFF_B08 (OFF_WK + 2560)      // 22528 : fp8 gates B, 40960 bytes
#define SZ_B08B (NW*TPW*512)         // 40960 bytes
#define OFF_F8 (OFF_B08 + 20480)     // 43008 : fp8 h B region
#define SZ_F8B (NW*10*TPW*512)       // 409600 bytes: [wave][ks1-10][tile][512]
#define SW_SZ  (SZ_M1 + SZ_M2 + SZ_H)
#define SWM1   0
#define SWM2   (SZ_M1)
#define SWH    (SZ_M1 + SZ_M2)

typedef __attribute__((ext_vector_type(4))) float f32x4;
typedef __attribute__((ext_vector_type(8))) short bf16x8;
typedef long long ll8;

static __device__ __forceinline__ unsigned short f2bf(float f) {
    union { float f; unsigned u; } x; x.f = f;
    unsigned r = (x.u + 0x7fffu + ((x.u >> 16) & 1u)) >> 16;
    return (unsigned short)r;
}
static __device__ __forceinline__ unsigned char f2f8(float f) {
    return (unsigned char)(__builtin_amdgcn_cvt_pk_fp8_f32(f, 0.f, 0, false) & 0xff);
}
static __device__ __forceinline__ float ftanh(float v) {
    float e = __builtin_amdgcn_exp2f(v * 2.8853900817779268f);
    return 1.f - 2.f * __builtin_amdgcn_rcpf(e + 1.f);
}
static __device__ __forceinline__ int zcol(int c) { return (c & 3) * 300 + (c >> 2); }

// LDS-ordering barrier WITHOUT vmcnt drain (no cross-thread global dataflow in-kernel).
#define BARRIER() asm volatile("s_waitcnt lgkmcnt(0)\n\ts_barrier" ::: "memory")

// fp8 gates B: [wave8][tile10][512] bytes; tile = w + 8*i; rows 0..23 = wk (24=comb excluded)
__global__ __launch_bounds__(256) void conv_b08(
    const float* __restrict__ wk, unsigned char* __restrict__ dst8)
{
    int idx = blockIdx.x * 256 + threadIdx.x;
    if (idx >= SZ_B08B) return;
    int j = idx & 7, n = (idx >> 3) & 15, kg = (idx >> 7) & 3, q = idx >> 9;
    int i = q % TPW, w = q / TPW;
    int k = kg * 8 + j, c = (w + NW * i) * 16 + n;
    float v = (k < 24 && c < 1200) ? wk[k * 1200 + zcol(c)] : 0.f;
    dst8[idx] = f2f8(v);
}

// fp8 h-part B: [wave8][ks1..10][tile10][512] bytes; tile = w + 8*i; u = k-32
__global__ __launch_bounds__(256) void conv_b8(
    const float* __restrict__ wr, unsigned char* __restrict__ dst8)
{
    int idx = blockIdx.x * 256 + threadIdx.x;
    if (idx >= SZ_F8B) return;
    int j = idx & 7, n = (idx >> 3) & 15, kg = (idx >> 7) & 3, q = idx >> 9;
    int i = q % TPW, ks1 = (q / TPW) % 10, w = q / (TPW * 10);
    int k = (ks1 + 1) * 32 + kg * 8 + j, c = (w + NW * i) * 16 + n;
    float v = (k >= 32 && k < 332 && c < 1200) ? wr[(k - 32) * 1200 + zcol(c)] : 0.f;
    dst8[idx] = f2f8(v);
}

// bz (zcol order) and wk[24] row (zcol order)
__global__ __launch_bounds__(256) void conv_misc(
    const float* __restrict__ wk, const float* __restrict__ bz,
    float* __restrict__ bzdst, float* __restrict__ wkdst)
{
    int i = blockIdx.x * 256 + threadIdx.x;
    if (i >= 1280) return;
    float vb = 0.f, vw = 0.f;
    if (i < 1200) {
        int oc = zcol(i);
        vb = bz[oc];
        vw = wk[24 * 1200 + oc];
    }
    bzdst[i] = vb;
    wkdst[i] = vw;
}

__global__ __launch_bounds__(256) void conv_gen(
    const float* __restrict__ W, unsigned short* __restrict__ dst,
    int K, int N, int nks, int total)
{
    int idx = blockIdx.x * 256 + threadIdx.x;
    if (idx >= total) return;
    int j = idx & 7, n = (idx >> 3) & 15, kg = (idx >> 7) & 3, qq = idx >> 9;
    int ks = qq % nks, nt = qq / nks;
    int k = ks * 32 + kg * 8 + j, col = nt * 16 + n;
    float v = (k < K && col < N) ? W[k * N + col] : 0.f;
    dst[idx] = f2bf(v);
}

// heads B: K'=352, h at k=32..331 (u=k-32); bias row at k=332 (pairs with Hbf col 332 = 1.0)
__global__ __launch_bounds__(256) void conv_heads(
    const float* __restrict__ wa, const float* __restrict__ wm,
    const float* __restrict__ wsg, const float* __restrict__ ba,
    const float* __restrict__ bm, const float* __restrict__ bs,
    unsigned short* __restrict__ dst)
{
    int idx = blockIdx.x * 256 + threadIdx.x;
    if (idx >= SZ_H) return;
    int j = idx & 7, n = (idx >> 3) & 15, kg = (idx >> 7) & 3, qq = idx >> 9;
    int ks = qq % NKS, nt = qq / NKS;
    int k = ks * 32 + kg * 8 + j, col = nt * 16 + n;
    float v = 0.f;
    if (col < 24) {
        if (k >= 32 && k < 332) {
            int u = k - 32, h = col >> 3, m = col & 7;
            const float* W = (h == 0) ? wa : (h == 1) ? wm : wsg;
            v = W[u * 8 + m];
        } else if (k == 332) {
            v = (col < 8) ? ba[col] : (col < 16) ? bm[col - 8] : bs[col - 16];
        }
    }
    dst[idx] = f2bf(v);
}

#define MFMA   __builtin_amdgcn_mfma_f32_16x16x32_bf16
#define MFMA8  __builtin_amdgcn_mfma_f32_16x16x32_fp8_fp8
#define LOG2E  1.4426950408889634f

// One depth-2 pipelined ks-pair of the h-GEMM (exact r18 pr-loop body).
// Enters with bbA = batch(KSA); loads bbB = batch(KSA+1) (consumed in-site);
// if LOADNEXT, leaves bbA = batch(KSA+2) in flight for the next site.
#define KSPAIR(KSA, PP, LOADNEXT) do {                                        \
    const unsigned char* bp_ = bw8 + ((KSA) - 1) * (TPW * 512);               \
    const unsigned char* af_ = &Af8[PP][0][0] + arow * F8ROW + akg * 8;       \
    ll8 bbB_[TPW];                                                            \
    _Pragma("unroll")                                                         \
    for (int i = 0; i < TPW; ++i)                                             \
        bbB_[i] = *(const ll8*)(bp_ + (TPW * 512) + i * 512);                 \
    ll8 a8a_ = *(const ll8*)(af_ + (KSA) * 32);                               \
    _Pragma("unroll")                                                         \
    for (int i = 0; i < TPW; ++i)                                             \
        acc[i] = MFMA8(a8a_, bbA[i], acc[i], 0, 0, 0);                        \
    if (LOADNEXT) {                                                           \
        _Pragma("unroll")                                                     \
        for (int i = 0; i < TPW; ++i)                                         \
            bbA[i] = *(const ll8*)(bp_ + 2 * (TPW * 512) + i * 512);          \
    }                                                                         \
    ll8 a8b_ = *(const ll8*)(af_ + ((KSA) + 1) * 32);                         \
    _Pragma("unroll")                                                         \
    for (int i = 0; i < TPW; ++i)                                             \
        acc[i] = MFMA8(a8b_, bbB_[i], acc[i], 0, 0, 0);                       \
} while (0)

__global__ __launch_bounds__(NT, 2)
void dilstm(
    const float* __restrict__ x,
    const unsigned short* __restrict__ wf,
    const float* __restrict__ b1v,
    const float* __restrict__ b2v,
    float* __restrict__ out)
{
    __shared__ unsigned short Hbf[RPB][HROW];              // bf16 h (heads A); col 332 = 1.0
    __shared__ __attribute__((aligned(16))) unsigned char Af8[2][RPB][F8ROW]; // fp8 h at 32..331
    __shared__ __attribute__((aligned(16))) unsigned char G2b8[RPB][G2ROW];   // fp8 gates 0..23
    __shared__ unsigned short Gbf[RPB][GROW];
    __shared__ unsigned short G1b[RPB][GROW];
    __shared__ float Sc[RPB][24];
    __shared__ float Sc2[RPB][24];
    __shared__ float BzS[1280];
    __shared__ float WkS[1280];
    __shared__ float CombS[RPB];
    __shared__ float Zw[NW][2][16][20];                    // per-wave z staging, [row][col] (dbuf)
    __shared__ unsigned short SW[SW_SZ];

    const int t = threadIdx.x;
    const int lane = t & 63, wv = t >> 6;
    const int arow = lane & 15, akg = lane >> 4;
    const int crow0 = akg * 4;
    const int u_l = lane & 3, rr = lane >> 2;
    const int row0 = blockIdx.x * RPB;

    for (int i = t; i < RPB * HROW; i += NT) ((unsigned short*)Hbf)[i] = 0;
    for (int i = t; i < 2 * RPB * F8ROW; i += NT) ((unsigned char*)Af8)[i] = 0;
    for (int i = t; i < RPB * G2ROW; i += NT) ((unsigned char*)G2b8)[i] = 0;
    for (int i = t; i < RPB * GROW; i += NT) { ((unsigned short*)Gbf)[i] = 0; ((unsigned short*)G1b)[i] = 0; }
    for (int i = t; i < SW_SZ; i += NT) SW[i] = wf[OFF_M1 + i];
    {
        const float* bzp = (const float*)(wf + OFF_BZ);
        const float* wkp = (const float*)(wf + OFF_WK);
        for (int i = t; i < 1280; i += NT) { BzS[i] = bzp[i]; WkS[i] = wkp[i]; }
    }
    if (t < RPB) Hbf[t][332] = f2bf(1.f);   // bias column for heads

    float m1bias = 0.f, m2bias = 0.f;
    {
        int c1 = wv * 16 + arow;
        if (wv < 4 && c1 < 50) m1bias = b1v[c1];
        if (wv < 2 && c1 < 24) m2bias = b2v[c1];
    }

    float creg[TPW];
    #pragma unroll
    for (int i = 0; i < TPW; ++i) creg[i] = 0.f;

    const unsigned char* bw08 = (const unsigned char*)(wf + OFF_B08) + wv * (TPW * 512) + (lane << 3);
    const unsigned char* bw8  = (const unsigned char*)(wf + OFF_F8) + (size_t)wv * (100 * 512) + (lane << 3);

    // persistent h-GEMM state: accumulator + depth-2 ring register
    f32x4 acc[TPW];
    #pragma unroll
    for (int i = 0; i < TPW; ++i) acc[i] = (f32x4){0.f, 0.f, 0.f, 0.f};
    ll8 bbA[TPW];
    #pragma unroll
    for (int i = 0; i < TPW; ++i)                       // prime batch(ks7) for ts=0 P1-site
        bbA[i] = *(const ll8*)(bw8 + 6 * (TPW * 512) + i * 512);

    const int rA = t / 25, eA = t - (t / 25) * 25;
    float combreg = 0.f, xreg = 0.f;
    if (t < RPB * NFEAT) xreg = x[((size_t)(row0 + rA) * TT) * NFEAT + eA];
    __syncthreads();

    // initial gate-input build (prev = 0)
    if (t < RPB * NFEAT) {
        if (eA < 24) {
            Gbf[rA][eA] = f2bf(xreg);
        } else {
            float comb = xreg;
            combreg = comb;
            float denom = fmaxf(comb, 1e-8f);
            Gbf[rA][24] = f2bf(xreg / denom);
            CombS[rA] = comb;
        }
    }
    __syncthreads();

    for (int ts = 0; ts < TT; ++ts) {
        const int p = ts & 1;

        // ---- P1: MLP1 + x prefetch  ||  h-GEMM ks7-8 of z(ts) ----
        if (t < RPB * NFEAT && ts + 1 < TT)
            xreg = x[((size_t)(row0 + rA) * TT + (ts + 1)) * NFEAT + eA];
        if (wv < 4) {
            bf16x8 a0 = *(const bf16x8*)&Gbf[arow][akg * 8];
            bf16x8 a1 = *(const bf16x8*)&Gbf[arow][32 + akg * 8];
            bf16x8 b0 = *(const bf16x8*)&SW[SWM1 + (wv * 2 + 0) * 512 + (lane << 3)];
            f32x4 acc1 = {0.f, 0.f, 0.f, 0.f};
            acc1 = MFMA(a0, b0, acc1, 0, 0, 0);
            bf16x8 b1 = *(const bf16x8*)&SW[SWM1 + (wv * 2 + 1) * 512 + (lane << 3)];
            acc1 = MFMA(a1, b1, acc1, 0, 0, 0);
            int col = wv * 16 + arow;
            if (col < 50) {
                #pragma unroll
                for (int rg = 0; rg < 4; ++rg)
                    G1b[crow0 + rg][col] = f2bf(fmaxf(acc1[rg] + m1bias, 0.f));
            }
        }
        KSPAIR(7, p, 1);
        BARRIER();

        // ---- P2: MLP2 -> G2b8  ||  h-GEMM ks9-10 of z(ts) ----
        if (wv < 2) {
            bf16x8 a0 = *(const bf16x8*)&G1b[arow][akg * 8];
            bf16x8 a1 = *(const bf16x8*)&G1b[arow][32 + akg * 8];
            bf16x8 b0 = *(const bf16x8*)&SW[SWM2 + (wv * 2 + 0) * 512 + (lane << 3)];
            f32x4 acc2 = {0.f, 0.f, 0.f, 0.f};
            acc2 = MFMA(a0, b0, acc2, 0, 0, 0);
            bf16x8 b1 = *(const bf16x8*)&SW[SWM2 + (wv * 2 + 1) * 512 + (lane << 3)];
            acc2 = MFMA(a1, b1, acc2, 0, 0, 0);
            int col = wv * 16 + arow;
            if (col < 24) {
                #pragma unroll
                for (int rg = 0; rg < 4; ++rg)
                    G2b8[crow0 + rg][col] = f2f8(acc2[rg] + m2bias);
            }
        }
        KSPAIR(9, p, 0);
        BARRIER();

        // ---- P3: gates ks0 + cell epilogue -> h(ts); prime ring ks1 ----
        {
            // b08 loads first (consumed below), then prime bbA = batch(ks1)
            ll8 b08[TPW];
            #pragma unroll
            for (int i = 0; i < TPW; ++i)
                b08[i] = *(const ll8*)(bw08 + i * 512);
            #pragma unroll
            for (int i = 0; i < TPW; ++i)
                bbA[i] = *(const ll8*)(bw8 + i * 512);

            ll8 a8g = *(const ll8*)&G2b8[arow][akg * 8];
            #pragma unroll
            for (int i = 0; i < TPW; ++i)
                acc[i] = MFMA8(a8g, b08[i], acc[i], 0, 0, 0);

            // epilogue: transpose-write z, vector read, cell, h -> Hbf/Af8[p^1]
            float cmb = CombS[rr];
            #pragma unroll
            for (int rg = 0; rg < 4; ++rg)
                Zw[wv][0][crow0 + rg][arow] = acc[0][rg];
            #pragma unroll
            for (int i = 0; i < TPW; ++i) {
                if (i + 1 < TPW) {
                    #pragma unroll
                    for (int rg = 0; rg < 4; ++rg)
                        Zw[wv][(i + 1) & 1][crow0 + rg][arow] = acc[i + 1][rg];
                }
                f32x4 bz4 = *(const f32x4*)&BzS[(wv + NW * i) * 16 + 4 * u_l];
                f32x4 wk4 = *(const f32x4*)&WkS[(wv + NW * i) * 16 + 4 * u_l];
                f32x4 z4  = *(const f32x4*)&Zw[wv][i & 1][rr][4 * u_l];
                float zi = z4[0] + bz4[0] + cmb * wk4[0];
                float zf = z4[1] + bz4[1] + cmb * wk4[1];
                float zc = z4[2] + bz4[2] + cmb * wk4[2];
                float zo = z4[3] + bz4[3] + cmb * wk4[3];
                if (wv + NW * i < 75) {
                    float ig = fminf(fmaxf(0.2f * zi + 0.5f, 0.f), 1.f);
                    float fg = fminf(fmaxf(0.2f * zf + 0.5f, 0.f), 1.f);
                    float og = fminf(fmaxf(0.2f * zo + 0.5f, 0.f), 1.f);
                    float cn = fg * creg[i] + ig * ftanh(zc);
                    creg[i] = cn;
                    float hn = og * ftanh(cn);
                    int hb = (wv + NW * i) * 4 + u_l;
                    Hbf[rr][32 + hb] = f2bf(hn);
                    Af8[p ^ 1][rr][32 + hb] = f2f8(hn);
                }
                acc[i] = (f32x4){0.f, 0.f, 0.f, 0.f};   // restart for z(ts+1)
            }
        }
        BARRIER();

        // ---- P4: heads (4 waves)  ||  h-GEMM ks1-4 of z(ts+1) ----
        if (wv < 4) {
            const int ct = wv & 1, half = wv >> 1;
            const int k0 = 1 + 5 * half;
            f32x4 acc3 = {0.f, 0.f, 0.f, 0.f};
            #pragma unroll
            for (int q = 0; q < 5; ++q) {
                bf16x8 a = *(const bf16x8*)&Hbf[arow][(k0 + q) * 32 + akg * 8];
                bf16x8 b = *(const bf16x8*)&SW[SWH + (ct * NKS + k0 + q) * 512 + (lane << 3)];
                acc3 = MFMA(a, b, acc3, 0, 0, 0);
            }
            int col = ct * 16 + arow;
            if (col < 24) {
                if (half == 0) {
                    #pragma unroll
                    for (int rg = 0; rg < 4; ++rg)
                        Sc[crow0 + rg][col] = acc3[rg];
                } else {
                    #pragma unroll
                    for (int rg = 0; rg < 4; ++rg)
                        Sc2[crow0 + rg][col] = acc3[rg];
                }
            }
        }
        KSPAIR(1, p ^ 1, 1);
        KSPAIR(3, p ^ 1, 1);
        BARRIER();

        // ---- P5: softmax/out/Gbf(ts+1)  ||  h-GEMM ks5-6 of z(ts+1) ----
        if (t < RPB * NFEAT) {
            float v;
            if (eA < 8) {
                float s0 = Sc[rA][0] + Sc2[rA][0];
                float mx = s0;
                float sv[8]; sv[0] = s0;
                #pragma unroll
                for (int m = 1; m < 8; ++m) {
                    sv[m] = Sc[rA][m] + Sc2[rA][m];
                    mx = fmaxf(mx, sv[m]);
                }
                float sum = 0.f;
                #pragma unroll
                for (int m = 0; m < 8; ++m)
                    sum += __builtin_amdgcn_exp2f((sv[m] - mx) * LOG2E);
                v = __builtin_amdgcn_exp2f((sv[eA] - mx) * LOG2E) / sum;
            } else if (eA < 16) {
                v = Sc[rA][eA] + Sc2[rA][eA];
            } else if (eA < 24) {
                float s = Sc[rA][eA] + Sc2[rA][eA];
                v = (s > 0.f) ? (1.f + s) : __builtin_amdgcn_exp2f(s * LOG2E);
            } else {
                v = combreg;
            }
            out[((size_t)(row0 + rA) * TT + ts) * NFEAT + eA] = v;
            if (eA < 24) {
                Gbf[rA][eA]      = f2bf(xreg);
                Gbf[rA][25 + eA] = f2bf(v);
            } else {
                float comb = xreg + combreg;
                float denom = fmaxf(comb, 1e-8f);
                Gbf[rA][24] = f2bf(xreg / denom);
                Gbf[rA][49] = f2bf(combreg / denom);
                CombS[rA] = comb;
                combreg = comb;
            }
        }
        KSPAIR(5, p ^ 1, 1);   // trailing load = batch(ks7) for next iteration's P1
        BARRIER();
    }
}

extern "C" void kernel_launch(void* const* d_in, const int* in_sizes, int n_in,
                              void* d_out, int out_size, void* d_ws, size_t ws_size,
                              hipStream_t stream) {
    const float* x   = (const float*)d_in[0];
    const float* wk  = (const float*)d_in[1];
    const float* wr  = (const float*)d_in[2];
    const float* bz  = (const float*)d_in[3];
    const float* w1  = (const float*)d_in[4];
    const float* b1  = (const float*)d_in[5];
    const float* w2  = (const float*)d_in[6];
    const float* b2  = (const float*)d_in[7];
    const float* wa  = (const float*)d_in[8];
    const float* ba  = (const float*)d_in[9];
    const float* wm  = (const float*)d_in[10];
    const float* bm  = (const float*)d_in[11];
    const float* wsg = (const float*)d_in[12];
    const float* bs  = (const float*)d_in[13];
    float* out = (float*)d_out;
    unsigned short* wf = (unsigned short*)d_ws;
    unsigned char*  wf08 = (unsigned char*)(wf + OFF_B08);
    unsigned char*  wf8  = (unsigned char*)(wf + OFF_F8);
    float* bzdst = (float*)(wf + OFF_BZ);
    float* wkdst = (float*)(wf + OFF_WK);

    conv_b08<<<(SZ_B08B + 255) / 256, 256, 0, stream>>>(wk, wf08);
    conv_b8<<<(SZ_F8B + 255) / 256, 256, 0, stream>>>(wr, wf8);
    conv_misc<<<(1280 + 255) / 256, 256, 0, stream>>>(wk, bz, bzdst, wkdst);
    conv_gen<<<(SZ_M1 + 255) / 256, 256, 0, stream>>>(w1, wf + OFF_M1, 50, 50, 2, SZ_M1);
    conv_gen<<<(SZ_M2 + 255) / 256, 256, 0, stream>>>(w2, wf + OFF_M2, 50, 24, 2, SZ_M2);
    conv_heads<<<(SZ_H + 255) / 256, 256, 0, stream>>>(wa, wm, wsg, ba, bm, bs, wf + OFF_H);
    dilstm<<<NBLK, NT, 0, stream>>>(x, wf, b1, b2, out);
}

// Round 23
// 3615.488 us; speedup vs baseline: 2.7149x; 2.7149x over previous
//
#include <hip/hip_runtime.h>
#include <math.h>

#define BB 2048
#define TT 512
#define NFEAT 25
#define UNITS 300
#define RPB 16
#define NBLK (BB/RPB)    // 128
#define NT 1024
#define NW 16            // waves per block
#define NKS 11           // heads k-steps; fp8 h GEMM uses ks1-10
#define TPW 5            // tiles per wave (80 tiles / 16 waves)
#define HROW 360         // Hbf row stride (shorts); h at 32..331, 1.0 at 332
#define F8ROW 392        // Af8 row stride (bytes); h at 32..331
#define G2ROW 40         // G2b8 row stride (bytes); gates at 0..23
#define GROW 72

// d_ws layout (short offsets)
#define OFF_M1 0
#define SZ_M1  (4*2*512)             // 4096
#define OFF_M2 (OFF_M1 + SZ_M1)      // 4096
#define SZ_M2  (2*2*512)             // 2048
#define OFF_H  (OFF_M2 + SZ_M2)      // 6144
#define SZ_H   (2*NKS*512)           // 11264
#define OFF_BZ (OFF_H + SZ_H)        // 17408 : 1280 floats
#define OFF_WK (OFF_BZ + 2560)       // 19968 : 1280 floats
#define OFF_B08 (OFF_WK + 2560)      // 22528 : fp8 gates B, 40960 bytes
#define SZ_B08B (NW*TPW*512)         // 40960 bytes
#define OFF_F8 (OFF_B08 + 20480)     // 43008 : fp8 h B region
#define SZ_F8B (NW*10*TPW*512)       // 409600 bytes: [wave][ks1-10][tile][512]
#define SW_SZ  (SZ_M1 + SZ_M2 + SZ_H)
#define SWM1   0
#define SWM2   (SZ_M1)
#define SWH    (SZ_M1 + SZ_M2)

typedef __attribute__((ext_vector_type(4))) float f32x4;
typedef __attribute__((ext_vector_type(8))) short bf16x8;
typedef long long ll8;

static __device__ __forceinline__ unsigned short f2bf(float f) {
    union { float f; unsigned u; } x; x.f = f;
    unsigned r = (x.u + 0x7fffu + ((x.u >> 16) & 1u)) >> 16;
    return (unsigned short)r;
}
static __device__ __forceinline__ unsigned char f2f8(float f) {
    return (unsigned char)(__builtin_amdgcn_cvt_pk_fp8_f32(f, 0.f, 0, false) & 0xff);
}
static __device__ __forceinline__ float ftanh(float v) {
    float e = __builtin_amdgcn_exp2f(v * 2.8853900817779268f);
    return 1.f - 2.f * __builtin_amdgcn_rcpf(e + 1.f);
}
static __device__ __forceinline__ int zcol(int c) { return (c & 3) * 300 + (c >> 2); }

// LDS-ordering barrier WITHOUT vmcnt drain (no cross-thread global dataflow in-kernel).
#define BARRIER() asm volatile("s_waitcnt lgkmcnt(0)\n\ts_barrier" ::: "memory")

// fp8 gates B: [wave16][tile5][512] bytes; tile = w + 16*i; rows 0..23 = wk (24=comb excluded)
__global__ __launch_bounds__(256) void conv_b08(
    const float* __restrict__ wk, unsigned char* __restrict__ dst8)
{
    int idx = blockIdx.x * 256 + threadIdx.x;
    if (idx >= SZ_B08B) return;
    int j = idx & 7, n = (idx >> 3) & 15, kg = (idx >> 7) & 3, q = idx >> 9;
    int i = q % TPW, w = q / TPW;
    int k = kg * 8 + j, c = (w + NW * i) * 16 + n;
    float v = (k < 24 && c < 1200) ? wk[k * 1200 + zcol(c)] : 0.f;
    dst8[idx] = f2f8(v);
}

// fp8 h-part B: [wave16][ks1..10][tile5][512] bytes; tile = w + 16*i; u = k-32
__global__ __launch_bounds__(256) void conv_b8(
    const float* __restrict__ wr, unsigned char* __restrict__ dst8)
{
    int idx = blockIdx.x * 256 + threadIdx.x;
    if (idx >= SZ_F8B) return;
    int j = idx & 7, n = (idx >> 3) & 15, kg = (idx >> 7) & 3, q = idx >> 9;
    int i = q % TPW, ks1 = (q / TPW) % 10, w = q / (TPW * 10);
    int k = (ks1 + 1) * 32 + kg * 8 + j, c = (w + NW * i) * 16 + n;
    float v = (k >= 32 && k < 332 && c < 1200) ? wr[(k - 32) * 1200 + zcol(c)] : 0.f;
    dst8[idx] = f2f8(v);
}

// bz (zcol order) and wk[24] row (zcol order)
__global__ __launch_bounds__(256) void conv_misc(
    const float* __restrict__ wk, const float* __restrict__ bz,
    float* __restrict__ bzdst, float* __restrict__ wkdst)
{
    int i = blockIdx.x * 256 + threadIdx.x;
    if (i >= 1280) return;
    float vb = 0.f, vw = 0.f;
    if (i < 1200) {
        int oc = zcol(i);
        vb = bz[oc];
        vw = wk[24 * 1200 + oc];
    }
    bzdst[i] = vb;
    wkdst[i] = vw;
}

__global__ __launch_bounds__(256) void conv_gen(
    const float* __restrict__ W, unsigned short* __restrict__ dst,
    int K, int N, int nks, int total)
{
    int idx = blockIdx.x * 256 + threadIdx.x;
    if (idx >= total) return;
    int j = idx & 7, n = (idx >> 3) & 15, kg = (idx >> 7) & 3, qq = idx >> 9;
    int ks = qq % nks, nt = qq / nks;
    int k = ks * 32 + kg * 8 + j, col = nt * 16 + n;
    float v = (k < K && col < N) ? W[k * N + col] : 0.f;
    dst[idx] = f2bf(v);
}

// heads B: K'=352, h at k=32..331 (u=k-32); bias row at k=332 (pairs with Hbf col 332 = 1.0)
__global__ __launch_bounds__(256) void conv_heads(
    const float* __restrict__ wa, const float* __restrict__ wm,
    const float* __restrict__ wsg, const float* __restrict__ ba,
    const float* __restrict__ bm, const float* __restrict__ bs,
    unsigned short* __restrict__ dst)
{
    int idx = blockIdx.x * 256 + threadIdx.x;
    if (idx >= SZ_H) return;
    int j = idx & 7, n = (idx >> 3) & 15, kg = (idx >> 7) & 3, qq = idx >> 9;
    int ks = qq % NKS, nt = qq / NKS;
    int k = ks * 32 + kg * 8 + j, col = nt * 16 + n;
    float v = 0.f;
    if (col < 24) {
        if (k >= 32 && k < 332) {
            int u = k - 32, h = col >> 3, m = col & 7;
            const float* W = (h == 0) ? wa : (h == 1) ? wm : wsg;
            v = W[u * 8 + m];
        } else if (k == 332) {
            v = (col < 8) ? ba[col] : (col < 16) ? bm[col - 8] : bs[col - 16];
        }
    }
    dst[idx] = f2bf(v);
}

#define MFMA   __builtin_amdgcn_mfma_f32_16x16x32_bf16
#define MFMA8  __builtin_amdgcn_mfma_f32_16x16x32_fp8_fp8
#define LOG2E  1.4426950408889634f

__global__ __launch_bounds__(NT)
void dilstm(
    const float* __restrict__ x,
    const unsigned short* __restrict__ wf,
    const float* __restrict__ b1v,
    const float* __restrict__ b2v,
    float* __restrict__ out)
{
    __shared__ unsigned short Hbf[RPB][HROW];              // bf16 h (heads A); col 332 = 1.0
    __shared__ __attribute__((aligned(16))) unsigned char Af8[2][RPB][F8ROW]; // fp8 h at 32..331
    __shared__ __attribute__((aligned(16))) unsigned char G2b8[RPB][G2ROW];   // fp8 gates 0..23
    __shared__ unsigned short Gbf[RPB][GROW];
    __shared__ unsigned short G1b[RPB][GROW];
    __shared__ float Sc[RPB][24];
    __shared__ float Sc2[RPB][24];
    __shared__ float BzS[1280];
    __shared__ float WkS[1280];
    __shared__ float CombS[RPB];
    __shared__ float Zw[NW][2][16][20];                    // per-wave z staging, [row][col] (dbuf)
    __shared__ unsigned short SW[SW_SZ];

    const int t = threadIdx.x;
    const int lane = t & 63, wv = t >> 6;
    const int arow = lane & 15, akg = lane >> 4;
    const int crow0 = akg * 4;
    const int u_l = lane & 3, rr = lane >> 2;
    const int row0 = blockIdx.x * RPB;

    for (int i = t; i < RPB * HROW; i += NT) ((unsigned short*)Hbf)[i] = 0;
    for (int i = t; i < 2 * RPB * F8ROW; i += NT) ((unsigned char*)Af8)[i] = 0;
    for (int i = t; i < RPB * G2ROW; i += NT) ((unsigned char*)G2b8)[i] = 0;
    for (int i = t; i < RPB * GROW; i += NT) { ((unsigned short*)Gbf)[i] = 0; ((unsigned short*)G1b)[i] = 0; }
    for (int i = t; i < SW_SZ; i += NT) SW[i] = wf[OFF_M1 + i];
    {
        const float* bzp = (const float*)(wf + OFF_BZ);
        const float* wkp = (const float*)(wf + OFF_WK);
        for (int i = t; i < 1280; i += NT) { BzS[i] = bzp[i]; WkS[i] = wkp[i]; }
    }
    if (t < RPB) Hbf[t][332] = f2bf(1.f);   // bias column for heads

    float m1bias = 0.f, m2bias = 0.f;
    {
        int c1 = (wv & 3) * 16 + arow;
        if (wv < 4 && c1 < 50) m1bias = b1v[c1];
        if (wv < 2 && c1 < 24) m2bias = b2v[c1];
    }

    float creg[TPW];
    #pragma unroll
    for (int i = 0; i < TPW; ++i) creg[i] = 0.f;

    const unsigned char* bw08 = (const unsigned char*)(wf + OFF_B08) + wv * (TPW * 512) + (lane << 3);
    const unsigned char* bw8  = (const unsigned char*)(wf + OFF_F8) + (size_t)wv * (10 * TPW * 512) + (lane << 3);

    const int rA = t / 25, eA = t - (t / 25) * 25;
    float combreg = 0.f, xreg = 0.f;
    if (t < RPB * NFEAT) xreg = x[((size_t)(row0 + rA) * TT) * NFEAT + eA];
    __syncthreads();

    // initial gate-input build (prev = 0)
    if (t < RPB * NFEAT) {
        if (eA < 24) {
            Gbf[rA][eA] = f2bf(xreg);
        } else {
            float comb = xreg;
            combreg = comb;
            float denom = fmaxf(comb, 1e-8f);
            Gbf[rA][24] = f2bf(xreg / denom);
            CombS[rA] = comb;
        }
    }
    __syncthreads();

    for (int ts = 0; ts < TT; ++ts) {
        const int p = ts & 1;

        // ---- P1: B-prefetch (fp8 gates + first fp8 h batch) + x prefetch + MLP1 ----
        ll8 b08[TPW], bbA[TPW];
        #pragma unroll
        for (int i = 0; i < TPW; ++i)
            b08[i] = *(const ll8*)(bw08 + i * 512);
        #pragma unroll
        for (int i = 0; i < TPW; ++i)
            bbA[i] = *(const ll8*)(bw8 + i * 512);
        if (t < RPB * NFEAT && ts + 1 < TT)
            xreg = x[((size_t)(row0 + rA) * TT + (ts + 1)) * NFEAT + eA];

        if (wv < 4) {
            bf16x8 a0 = *(const bf16x8*)&Gbf[arow][akg * 8];
            bf16x8 a1 = *(const bf16x8*)&Gbf[arow][32 + akg * 8];
            bf16x8 b0 = *(const bf16x8*)&SW[SWM1 + (wv * 2 + 0) * 512 + (lane << 3)];
            bf16x8 b1 = *(const bf16x8*)&SW[SWM1 + (wv * 2 + 1) * 512 + (lane << 3)];
            f32x4 acc1 = {0.f, 0.f, 0.f, 0.f};
            acc1 = MFMA(a0, b0, acc1, 0, 0, 0);
            acc1 = MFMA(a1, b1, acc1, 0, 0, 0);
            int col = wv * 16 + arow;
            if (col < 50) {
                #pragma unroll
                for (int rg = 0; rg < 4; ++rg)
                    G1b[crow0 + rg][col] = f2bf(fmaxf(acc1[rg] + m1bias, 0.f));
            }
        }
        BARRIER();

        // ---- P2: MLP2 (waves 0-1) -> G2b8 (fp8 gates) ----
        if (wv < 2) {
            bf16x8 a0 = *(const bf16x8*)&G1b[arow][akg * 8];
            bf16x8 a1 = *(const bf16x8*)&G1b[arow][32 + akg * 8];
            bf16x8 b0 = *(const bf16x8*)&SW[SWM2 + (wv * 2 + 0) * 512 + (lane << 3)];
            bf16x8 b1 = *(const bf16x8*)&SW[SWM2 + (wv * 2 + 1) * 512 + (lane << 3)];
            f32x4 acc2 = {0.f, 0.f, 0.f, 0.f};
            acc2 = MFMA(a0, b0, acc2, 0, 0, 0);
            acc2 = MFMA(a1, b1, acc2, 0, 0, 0);
            int col = wv * 16 + arow;
            if (col < 24) {
                #pragma unroll
                for (int rg = 0; rg < 4; ++rg)
                    G2b8[crow0 + rg][col] = f2f8(acc2[rg] + m2bias);
            }
        }
        BARRIER();

        // ---- P3: GEMM (ks0 fp8 gates + ks1-10 fp8 h) + cell epilogue ----
        {
            f32x4 acc[TPW];
            #pragma unroll
            for (int i = 0; i < TPW; ++i) acc[i] = (f32x4){0.f, 0.f, 0.f, 0.f};

            // ks0: gates, fp8 (B prefetched in P1, still in flight - waited at use)
            {
                ll8 a8g = *(const ll8*)&G2b8[arow][akg * 8];
                #pragma unroll
                for (int i = 0; i < TPW; ++i)
                    acc[i] = MFMA8(a8g, b08[i], acc[i], 0, 0, 0);
            }
            // ks1-10: h, fp8, depth-2 pipeline; both A-fragment LDS reads issued
            // together at iteration top so their latencies overlap.
            {
                const unsigned char* af8p = &Af8[p][0][0] + arow * F8ROW + akg * 8;
                const unsigned char* bp = bw8;
                ll8 bbB[TPW];
                #pragma unroll 1
                for (int pr = 0; pr < 5; ++pr) {
                    const int ks = 2 * pr + 1;
                    ll8 a8a = *(const ll8*)(af8p + ks * 32);
                    ll8 a8b = *(const ll8*)(af8p + ks * 32 + 32);
                    #pragma unroll
                    for (int i = 0; i < TPW; ++i)
                        bbB[i] = *(const ll8*)(bp + 2560 + i * 512);
                    #pragma unroll
                    for (int i = 0; i < TPW; ++i)
                        acc[i] = MFMA8(a8a, bbA[i], acc[i], 0, 0, 0);
                    if (pr < 4) {
                        #pragma unroll
                        for (int i = 0; i < TPW; ++i)
                            bbA[i] = *(const ll8*)(bp + 5120 + i * 512);
                    }
                    #pragma unroll
                    for (int i = 0; i < TPW; ++i)
                        acc[i] = MFMA8(a8b, bbB[i], acc[i], 0, 0, 0);
                    bp += 5120;
                }
            }

            // epilogue: transpose-write z to Zw[row][col] (4 scalar writes),
            // read one f32x4 per tile (short dep chain; <=2-way banks both sides)
            float cmb = CombS[rr];
            #pragma unroll
            for (int rg = 0; rg < 4; ++rg)
                Zw[wv][0][crow0 + rg][arow] = acc[0][rg];
            #pragma unroll
            for (int i = 0; i < TPW; ++i) {
                if (i + 1 < TPW) {
                    #pragma unroll
                    for (int rg = 0; rg < 4; ++rg)
                        Zw[wv][(i + 1) & 1][crow0 + rg][arow] = acc[i + 1][rg];
                }
                f32x4 bz4 = *(const f32x4*)&BzS[(wv + NW * i) * 16 + 4 * u_l];
                f32x4 wk4 = *(const f32x4*)&WkS[(wv + NW * i) * 16 + 4 * u_l];
                f32x4 z4  = *(const f32x4*)&Zw[wv][i & 1][rr][4 * u_l];
                float zi = z4[0] + bz4[0] + cmb * wk4[0];
                float zf = z4[1] + bz4[1] + cmb * wk4[1];
                float zc = z4[2] + bz4[2] + cmb * wk4[2];
                float zo = z4[3] + bz4[3] + cmb * wk4[3];
                if (wv + NW * i < 75) {
                    float ig = fminf(fmaxf(0.2f * zi + 0.5f, 0.f), 1.f);
                    float fg = fminf(fmaxf(0.2f * zf + 0.5f, 0.f), 1.f);
                    float og = fminf(fmaxf(0.2f * zo + 0.5f, 0.f), 1.f);
                    float cn = fg * creg[i] + ig * ftanh(zc);
                    creg[i] = cn;
                    float hn = og * ftanh(cn);
                    int hb = (wv + NW * i) * 4 + u_l;
                    Hbf[rr][32 + hb] = f2bf(hn);
                    Af8[p ^ 1][rr][32 + hb] = f2f8(hn);
                }
            }
        }
        BARRIER();

        // ---- P4: heads on 4 waves (A-fragments batch-prefetched) ----
        if (wv < 4) {
            const int ct = wv & 1, half = wv >> 1;
            const int k0 = 1 + 5 * half;
            bf16x8 ah[5];
            #pragma unroll
            for (int q = 0; q < 5; ++q)
                ah[q] = *(const bf16x8*)&Hbf[arow][(k0 + q) * 32 + akg * 8];
            f32x4 acc3 = {0.f, 0.f, 0.f, 0.f};
            #pragma unroll
            for (int q = 0; q < 5; ++q) {
                bf16x8 b = *(const bf16x8*)&SW[SWH + (ct * NKS + k0 + q) * 512 + (lane << 3)];
                acc3 = MFMA(ah[q], b, acc3, 0, 0, 0);
            }
            int col = ct * 16 + arow;
            if (col < 24) {
                if (half == 0) {
                    #pragma unroll
                    for (int rg = 0; rg < 4; ++rg)
                        Sc[crow0 + rg][col] = acc3[rg];
                } else {
                    #pragma unroll
                    for (int rg = 0; rg < 4; ++rg)
                        Sc2[crow0 + rg][col] = acc3[rg];
                }
            }
        }
        BARRIER();

        // ---- P5: softmax/nnelu + out + next-step gate input ----
        if (t < RPB * NFEAT) {
            float v;
            if (eA < 8) {
                float s0 = Sc[rA][0] + Sc2[rA][0];
                float mx = s0;
                float sv[8]; sv[0] = s0;
                #pragma unroll
                for (int m = 1; m < 8; ++m) {
                    sv[m] = Sc[rA][m] + Sc2[rA][m];
                    mx = fmaxf(mx, sv[m]);
                }
                float sum = 0.f;
                #pragma unroll
                for (int m = 0; m < 8; ++m)
                    sum += __builtin_amdgcn_exp2f((sv[m] - mx) * LOG2E);
                v = __builtin_amdgcn_exp2f((sv[eA] - mx) * LOG2E) / sum;
            } else if (eA < 16) {
                v = Sc[rA][eA] + Sc2[rA][eA];
            } else if (eA < 24) {
                float s = Sc[rA][eA] + Sc2[rA][eA];
                v = (s > 0.f) ? (1.f + s) : __builtin_amdgcn_exp2f(s * LOG2E);
            } else {
                v = combreg;
            }
            out[((size_t)(row0 + rA) * TT + ts) * NFEAT + eA] = v;
            if (eA < 24) {
                Gbf[rA][eA]      = f2bf(xreg);
                Gbf[rA][25 + eA] = f2bf(v);
            } else {
                float comb = xreg + combreg;
                float denom = fmaxf(comb, 1e-8f);
                Gbf[rA][24] = f2bf(xreg / denom);
                Gbf[rA][49] = f2bf(combreg / denom);
                CombS[rA] = comb;
                combreg = comb;
            }
        }
        BARRIER();
    }
}

extern "C" void kernel_launch(void* const* d_in, const int* in_sizes, int n_in,
                              void* d_out, int out_size, void* d_ws, size_t ws_size,
                              hipStream_t stream) {
    const float* x   = (const float*)d_in[0];
    const float* wk  = (const float*)d_in[1];
    const float* wr  = (const float*)d_in[2];
    const float* bz  = (const float*)d_in[3];
    const float* w1  = (const float*)d_in[4];
    const float* b1  = (const float*)d_in[5];
    const float* w2  = (const float*)d_in[6];
    const float* b2  = (const float*)d_in[7];
    const float* wa  = (const float*)d_in[8];
    const float* ba  = (const float*)d_in[9];
    const float* wm  = (const float*)d_in[10];
    const float* bm  = (const float*)d_in[11];
    const float* wsg = (const float*)d_in[12];
    const float* bs  = (const float*)d_in[13];
    float* out = (float*)d_out;
    unsigned short* wf = (unsigned short*)d_ws;
    unsigned char*  wf08 = (unsigned char*)(wf + OFF_B08);
    unsigned char*  wf8  = (unsigned char*)(wf + OFF_F8);
    float* bzdst = (float*)(wf + OFF_BZ);
    float* wkdst = (float*)(wf + OFF_WK);

    conv_b08<<<(SZ_B08B + 255) / 256, 256, 0, stream>>>(wk, wf08);
    conv_b8<<<(SZ_F8B + 255) / 256, 256, 0, stream>>>(wr, wf8);
    conv_misc<<<(1280 + 255) / 256, 256, 0, stream>>>(wk, bz, bzdst, wkdst);
    conv_gen<<<(SZ_M1 + 255) / 256, 256, 0, stream>>>(w1, wf + OFF_M1, 50, 50, 2, SZ_M1);
    conv_gen<<<(SZ_M2 + 255) / 256, 256, 0, stream>>>(w2, wf + OFF_M2, 50, 24, 2, SZ_M2);
    conv_heads<<<(SZ_H + 255) / 256, 256, 0, stream>>>(wa, wm, wsg, ba, bm, bs, wf + OFF_H);
    dilstm<<<NBLK, NT, 0, stream>>>(x, wf, b1, b2, out);
}